// Round 14
// baseline (341.244 us; speedup 1.0000x reference)
//
#include <hip/hip_runtime.h>

// ---------------------------------------------------------------------------
// uOT loss (unbalanced Sinkhorn, eps=0.1, rho=1, 50 iters + extrapolation x2)
// 8 working blocks per sample, 512 threads (8 waves) per block.
// Grid = 64; sample = blockIdx.x & 7 (>=4 exit), peer b = blockIdx.x >> 3.
// With the measured XCD = blockIdx%8 round-robin, a sample's 8 peers share
// one XCD -> its L2 is their common coherent cache. Exchange transports:
//   FAST: sc0 (L1-bypass) store/load of (gen<<32|f32) words, contiguous
//         [par][t][8k] buffer — same-XCD L2 RTT ~0.15us.
//   SLOW: R11's agent-scope tagged words (always also written, R11-proven).
// Poll: fast for at most FAST_SPINS spins per generation; on exhaustion the
// thread PERMANENTLY revokes fast and uses the slow loop (unbounded-safe).
// R13's hang was an unbounded fast-only spin on a stale L2 line; here every
// control path terminates in the slow loop -> deadlock impossible. Payload
// bits + summation order identical on both paths -> tm bit-identical ->
// output independent of placement/timing (G16-safe).
// Compute skeleton = R11 verbatim (validated PASS absmax 0.0, 271us).
// ---------------------------------------------------------------------------

typedef __attribute__((ext_vector_type(4))) float f32x4;
typedef __attribute__((ext_vector_type(8))) short short8;

#define TAU_F     0.9090909090909091f     // rho/(rho+eps)
#define TEPS_F    0.09090909090909091f    // tau*eps == 1-tau (rho=1)
#define LAMB_F    0.005354280739427885f   // 0.8*sigmoid(-5)
#define NEG5L2E  -7.213475204444817f      // -(1/(2*eps)) * log2(e)
#define FAST_SPINS 128

static __device__ __forceinline__ float hexp2(float x) {
  float r; asm("v_exp_f32 %0, %1" : "=v"(r) : "v"(x)); return r;
}
static __device__ __forceinline__ float hlog2(float x) {
  float r; asm("v_log_f32 %0, %1" : "=v"(r) : "v"(x)); return r;
}
static __device__ __forceinline__ float powm(float x, float p) {  // x^p, x>0
  return hexp2(p * hlog2(x));
}
static __device__ __forceinline__ float pklo(unsigned u) {
  union { unsigned i; float f; } v; v.i = u << 16; return v.f;
}
static __device__ __forceinline__ float pkhi(unsigned u) {
  union { unsigned i; float f; } v; v.i = u & 0xffff0000u; return v.f;
}
static __device__ __forceinline__ unsigned cvtpk(float lo, float hi) {
  unsigned r;
  asm("v_cvt_pk_bf16_f32 %0, %1, %2" : "=v"(r) : "v"(lo), "v"(hi));
  return r;
}
static __device__ __forceinline__ f32x4 mfma16(uint4 a, uint4 b, f32x4 c) {
  return __builtin_amdgcn_mfma_f32_16x16x32_bf16(
      __builtin_bit_cast(short8, a), __builtin_bit_cast(short8, b), c, 0, 0, 0);
}
static __device__ __forceinline__ void st_sc0(unsigned long long* p,
                                              unsigned long long v) {
  asm volatile("global_store_dwordx2 %0, %1, off sc0"
               :: "v"(p), "v"(v) : "memory");
}

__global__ void __launch_bounds__(512, 2)
uot_kernel(const float* __restrict__ dens, const float* __restrict__ pts,
           float* __restrict__ out, unsigned long long* __restrict__ ws) {
  __shared__ float ymx[256], ymy[256], psi[256], nb[256], tb[256], tps[256];
  __shared__ float tp[2][256];
  __shared__ float red[8];
  __shared__ uint4 Vl4[320];                       // V: 64 rows x 80B (40 u16)
  unsigned short* Vl = (unsigned short*)Vl4;

  const int s = blockIdx.x & 7, b = blockIdx.x >> 3;
  if (s >= 4) return;                              // XCD slots 4-7 unused
  const int ib = b >> 2, jb = b & 3;
  const int i0 = ib * 64, j0 = jb * 32;
  const int t = threadIdx.x, l = t & 63, w = t >> 6;
  const int wi = w >> 1, wj = w & 1;   // f-GEMM frag: rows i0+wi*16, cols j0+wj*16
  const int ii = w >> 2, mi = w & 3;   // g-GEMM tile: rows ii*32 (local), cols mi*64
  const int lr = l & 15, lq = l >> 4;

  unsigned long long* tpair = ws + (size_t)s * 4096;          // slow [2p][8b][256]
  unsigned long long* tfast = ws + 16384 + (size_t)s * 4096;  // fast [2p][256t][8k]
  const float* dp = dens + s * 16384;
  const float* pp = pts + s * 512;

  if (t < 256) {
    ymx[t] = pp[2 * t] * (1.f / 256.f);
    ymy[t] = pp[2 * t + 1] * (1.f / 256.f);
    psi[t] = 1.f;
    nb[t]  = 1.f;
  }
  __syncthreads();

  // ---- register tables (iteration-invariant) ----
  uint4 A_f[8], B_f[8], B_g[4];
  uint2 A_t[2][4];
  float a_f[4];
  {
    float gxa = (i0 + wi * 16 + lr + 0.5f) * (1.f / 128.f);
    float gya = (j0 + wj * 16 + lr + 0.5f) * (1.f / 128.f);
    #pragma unroll
    for (int ks = 0; ks < 8; ++ks) {
      unsigned qa[4], qb[4];
      #pragma unroll
      for (int e4 = 0; e4 < 4; ++e4) {
        int m0 = ks * 32 + 8 * lq + 2 * e4;
        float dx0 = gxa - ymx[m0], dx1 = gxa - ymx[m0 + 1];
        float dy0 = gya - ymy[m0], dy1 = gya - ymy[m0 + 1];
        qa[e4] = cvtpk(hexp2(dx0 * dx0 * NEG5L2E), hexp2(dx1 * dx1 * NEG5L2E));
        qb[e4] = cvtpk(hexp2(dy0 * dy0 * NEG5L2E), hexp2(dy1 * dy1 * NEG5L2E));
      }
      A_f[ks] = make_uint4(qa[0], qa[1], qa[2], qa[3]);
      B_f[ks] = make_uint4(qb[0], qb[1], qb[2], qb[3]);
    }
    #pragma unroll
    for (int mt = 0; mt < 4; ++mt) {          // B_g: k = local j, col = m
      float ym = ymy[mi * 64 + mt * 16 + lr];
      unsigned q[4];
      #pragma unroll
      for (int e4 = 0; e4 < 4; ++e4) {
        float g0 = (j0 + 8 * lq + 2 * e4 + 0.5f) * (1.f / 128.f);
        float d0 = g0 - ym, d1 = d0 + (1.f / 128.f);
        q[e4] = cvtpk(hexp2(d0 * d0 * NEG5L2E), hexp2(d1 * d1 * NEG5L2E));
      }
      B_g[mt] = make_uint4(q[0], q[1], q[2], q[3]);
    }
    #pragma unroll
    for (int it = 0; it < 2; ++it)            // A_t: C/D layout of g-GEMM
      #pragma unroll
      for (int mt = 0; mt < 4; ++mt) {
        float ym = ymx[mi * 64 + mt * 16 + lr];
        float g0 = (i0 + ii * 32 + it * 16 + 4 * lq + 0.5f) * (1.f / 128.f);
        float d0 = g0 - ym, d1 = d0 + (1.f / 128.f);
        float d2 = d0 + (2.f / 128.f), d3 = d0 + (3.f / 128.f);
        A_t[it][mt].x = cvtpk(hexp2(d0 * d0 * NEG5L2E), hexp2(d1 * d1 * NEG5L2E));
        A_t[it][mt].y = cvtpk(hexp2(d2 * d2 * NEG5L2E), hexp2(d3 * d3 * NEG5L2E));
      }
    #pragma unroll
    for (int e = 0; e < 4; ++e)               // density frag (C/D layout)
      a_f[e] = fmaxf(dp[(i0 + wi * 16 + 4 * lq + e) * 128 + (j0 + wj * 16 + lr)],
                     1e-8f);
  }

  f32x4 fA;
  unsigned mygen = 0;
  int par = 0;
  bool use_fast = true;             // revoked permanently on first exhaustion

  // ---- f-update: fully register-fed, zero barriers ----
  auto f_update = [&]() {
    f32x4 acc = {0.f, 0.f, 0.f, 0.f};
    #pragma unroll
    for (int ks = 0; ks < 8; ++ks) {
      int mb = ks * 32 + 8 * lq;
      float4 p0 = *(const float4*)(psi + mb);
      float4 p1 = *(const float4*)(psi + mb + 4);
      const unsigned* ar = (const unsigned*)&A_f[ks];
      uint4 wf;
      wf.x = cvtpk(pklo(ar[0]) * p0.x, pkhi(ar[0]) * p0.y);
      wf.y = cvtpk(pklo(ar[1]) * p0.z, pkhi(ar[1]) * p0.w);
      wf.z = cvtpk(pklo(ar[2]) * p1.x, pkhi(ar[2]) * p1.y);
      wf.w = cvtpk(pklo(ar[3]) * p1.z, pkhi(ar[3]) * p1.w);
      acc = mfma16(wf, B_f[ks], acc);
    }
    fA = acc;
  };

  // ---- g-update. mode 0: phase-A; 1: phase-C; 2: residual ----
  auto g_update = [&](int mode) {
    // V build: V[i][j] = a * s^{-tau}  (block-local, bf16)
    #pragma unroll
    for (int e = 0; e < 4; ++e) {
      float phi = powm(fA[e], -TAU_F);
      int il = wi * 16 + 4 * lq + e;
      int jl = wj * 16 + lr;
      union { float f; unsigned i; } v; v.f = a_f[e] * phi;
      unsigned bi = v.i + 0x7fffu + ((v.i >> 16) & 1u);
      Vl[il * 40 + jl] = (unsigned short)(bi >> 16);
    }
    __syncthreads();
    // g-GEMM: K = 32 local j, single MFMA step per frag
    uint4 vfr[2];
    #pragma unroll
    for (int it = 0; it < 2; ++it)
      vfr[it] = *(const uint4*)(Vl + (ii * 32 + it * 16 + lr) * 40 + 8 * lq);
    f32x4 gA[2][4];
    #pragma unroll
    for (int it = 0; it < 2; ++it)
      #pragma unroll
      for (int mt = 0; mt < 4; ++mt) {
        f32x4 z = {0.f, 0.f, 0.f, 0.f};
        gA[it][mt] = mfma16(vfr[it], B_g[mt], z);
      }
    // t-partial: t^b_m = sum_{i local} A[i][m] * P[i][m]
    #pragma unroll
    for (int mt = 0; mt < 4; ++mt) {
      float acc = 0.f;
      #pragma unroll
      for (int it = 0; it < 2; ++it) {
        uint2 u = A_t[it][mt];
        acc += pklo(u.x) * gA[it][mt][0];
        acc += pkhi(u.x) * gA[it][mt][1];
        acc += pklo(u.y) * gA[it][mt][2];
        acc += pkhi(u.y) * gA[it][mt][3];
      }
      acc += __shfl_xor(acc, 16);
      acc += __shfl_xor(acc, 32);
      if (l < 16) tp[ii][mi * 64 + mt * 16 + lr] = acc;
    }
    __syncthreads();
    const unsigned target = mygen + 1;
    if (t < 256) {
      // publish own (gen|value) word on BOTH transports (identical bits)
      float own = tp[0][t] + tp[1][t];
      union { float f; unsigned i; } ov; ov.f = own;
      unsigned long long pu = ((unsigned long long)target << 32) | ov.i;
      st_sc0(&tfast[par * 2048 + t * 8 + b], pu);          // fast: same-XCD L2
      __hip_atomic_store(&tpair[par * 2048 + b * 256 + t], pu,
                         __ATOMIC_RELAXED, __HIP_MEMORY_SCOPE_AGENT);
      float tm = 0.f;
      bool got = false;
      if (use_fast) {
        // bounded fast poll: sc0 reads of this thread's contiguous 64B
        unsigned long long* fbase = &tfast[par * 2048 + t * 8];
        #pragma unroll 1
        for (int spin = 0; spin < FAST_SPINS; ++spin) {
          uint4 q0, q1, q2, q3;
          asm volatile(
            "global_load_dwordx4 %0, %4, off sc0\n\t"
            "global_load_dwordx4 %1, %4, off offset:16 sc0\n\t"
            "global_load_dwordx4 %2, %4, off offset:32 sc0\n\t"
            "global_load_dwordx4 %3, %4, off offset:48 sc0\n\t"
            "s_waitcnt vmcnt(0)"
            : "=&v"(q0), "=&v"(q1), "=&v"(q2), "=&v"(q3)
            : "v"(fbase) : "memory");
          if (q0.y >= target && q0.w >= target && q1.y >= target &&
              q1.w >= target && q2.y >= target && q2.w >= target &&
              q3.y >= target && q3.w >= target) {
            union { unsigned i; float f; } v0, v1, v2, v3, v4, v5, v6, v7;
            v0.i = q0.x; v1.i = q0.z; v2.i = q1.x; v3.i = q1.z;
            v4.i = q2.x; v5.i = q2.z; v6.i = q3.x; v7.i = q3.z;
            tm = ((((((v0.f + v1.f) + v2.f) + v3.f) + v4.f) + v5.f) + v6.f)
                 + v7.f;                         // k-order sum (matches slow)
            got = true;
            break;
          }
          __builtin_amdgcn_s_sleep(1);
        }
        if (!got) use_fast = false;   // revoke forever; slow path from now on
      }
      if (!got) {
        // R11-proven agent-scope poll (unbounded-safe)
        bool ok;
        do {
          ok = true; float ts = 0.f;
          #pragma unroll
          for (int k = 0; k < 8; ++k) {
            unsigned long long p =
                __hip_atomic_load(&tpair[par * 2048 + k * 256 + t],
                                  __ATOMIC_RELAXED, __HIP_MEMORY_SCOPE_AGENT);
            ok &= ((unsigned)(p >> 32) >= target);
            union { unsigned i; float f; } pv; pv.i = (unsigned)p;
            ts += pv.f;
          }
          if (ok) tm = ts;
          else __builtin_amdgcn_s_sleep(1);
        } while (!ok);
      }
      if (mode == 2) {
        float r   = psi[t] * tm - 1.f;               // residual (b=1 in phase A)
        float nbv = fmaxf(1.f + LAMB_F * r, 1e-8f);  // new_b
        nb[t] = nbv;
        psi[t] = nbv;                                // psi' for phase C start
      } else {
        float ps = powm(tm, -TAU_F);                 // t^{-tau}
        psi[t] = (mode == 1 ? nb[t] : 1.f) * ps;
        tb[t] = tm;
      }
    }
    mygen++;
    par ^= 1;
    __syncthreads();
  };

  // ---- two Sinkhorn runs ----
  #pragma unroll 1
  for (int phase = 0; phase < 2; ++phase) {
    #pragma unroll 1
    for (int iter = 0; iter < 51; ++iter) {
      f_update();
      if (iter < 50) g_update(phase);
    }
    if (phase == 0) g_update(2);
  }

  // ---- loss: 1.05 * ( sum_n a*(1-s^{tau*eps}) + sum_m nb*(1-t^{tau*eps}) ) ----
  float ls = 0.f;
  #pragma unroll
  for (int e = 0; e < 4; ++e)
    ls += a_f[e] * (1.f - powm(fA[e], TEPS_F));
  #pragma unroll
  for (int off = 32; off >= 1; off >>= 1) ls += __shfl_xor(ls, off);
  if (l == 0) red[w] = ls;
  __syncthreads();
  if (t < 256) tps[t] = nb[t] * (1.f - powm(tb[t], TEPS_F));
  __syncthreads();
  if (t < 64) {
    float v = (b == 0) ? (tps[t] + tps[t + 64] + tps[t + 128] + tps[t + 192])
                       : 0.f;
    #pragma unroll
    for (int off = 32; off >= 1; off >>= 1) v += __shfl_xor(v, off);
    if (t == 0) {
      float la = 0.f;
      #pragma unroll
      for (int k = 0; k < 8; ++k) la += red[k];
      atomicAdd(out, 1.05f * (la + v));
    }
  }
}

extern "C" void kernel_launch(void* const* d_in, const int* in_sizes, int n_in,
                              void* d_out, int out_size, void* d_ws, size_t ws_size,
                              hipStream_t stream) {
  const float* dens = (const float*)d_in[0];
  const float* pts  = (const float*)d_in[1];
  float* out = (float*)d_out;
  if (ws_size < 262144) return;   // 4 x (32KB slow + 32KB fast) pair buffers
  (void)hipMemsetAsync(d_out, 0, (size_t)out_size * sizeof(float), stream);
  (void)hipMemsetAsync(d_ws, 0, 262144, stream);   // gen tags must start at 0
  hipLaunchKernelGGL(uot_kernel, dim3(64), dim3(512), 0, stream,
                     dens, pts, out, (unsigned long long*)d_ws);
}

// Round 15
// 260.031 us; speedup vs baseline: 1.3123x; 1.3123x over previous
//
#include <hip/hip_runtime.h>

// ---------------------------------------------------------------------------
// uOT loss (unbalanced Sinkhorn, eps=0.1, rho=1, 50 iters + extrapolation x2)
// 8 blocks per sample (32 total), 512 threads (8 waves) per block.
// Block b of a sample owns tile i in [ib*64,+64), j in [jb*32,+32).
// Exchange: each block publishes t^b[256] as 64-bit (gen<<32|f32) atomic
// words — the generation tag rides with the value, so no fence/flag/extra
// round-trip. Readers poll their own 8 tagged words. Parity double-buffer
// makes the scheme race-free at depth 2.
// FINAL (R15): this R11-validated configuration is the session's best.
// Structural floor: 101 inherently-serial cross-CU exchanges (Gauss-Seidel
// t-dependency) x (~1.5us device-scope RTT + ~1.0us compute) ~= 250us.
// Falsified alternatives: fewer sweeps (R9/R10: reference endpoint is a
// trajectory, not a fixed point -> 41% error), 16-peer split (R12: +17%),
// same-XCD sc0 transport (R13 hang; R14 hybrid +26%).
//   f-update: S[i][j] = sum_m (psi_m*A[i][m])*B[j][m]   (MFMA, all reg-fed)
//   g-update: P[i][m] = sum_{j local} V[i][j]*B[j][m]   (MFMA, K=32, 1 step)
//             t^b_m = sum_{i local} A[i][m]*P[i][m]     (reg FMA + shfl)
// ---------------------------------------------------------------------------

typedef __attribute__((ext_vector_type(4))) float f32x4;
typedef __attribute__((ext_vector_type(8))) short short8;

#define TAU_F     0.9090909090909091f     // rho/(rho+eps)
#define TEPS_F    0.09090909090909091f    // tau*eps == 1-tau (rho=1)
#define LAMB_F    0.005354280739427885f   // 0.8*sigmoid(-5)
#define NEG5L2E  -7.213475204444817f      // -(1/(2*eps)) * log2(e)

static __device__ __forceinline__ float hexp2(float x) {
  float r; asm("v_exp_f32 %0, %1" : "=v"(r) : "v"(x)); return r;
}
static __device__ __forceinline__ float hlog2(float x) {
  float r; asm("v_log_f32 %0, %1" : "=v"(r) : "v"(x)); return r;
}
static __device__ __forceinline__ float powm(float x, float p) {  // x^p, x>0
  return hexp2(p * hlog2(x));
}
static __device__ __forceinline__ float pklo(unsigned u) {
  union { unsigned i; float f; } v; v.i = u << 16; return v.f;
}
static __device__ __forceinline__ float pkhi(unsigned u) {
  union { unsigned i; float f; } v; v.i = u & 0xffff0000u; return v.f;
}
static __device__ __forceinline__ unsigned cvtpk(float lo, float hi) {
  unsigned r;
  asm("v_cvt_pk_bf16_f32 %0, %1, %2" : "=v"(r) : "v"(lo), "v"(hi));
  return r;
}
static __device__ __forceinline__ f32x4 mfma16(uint4 a, uint4 b, f32x4 c) {
  return __builtin_amdgcn_mfma_f32_16x16x32_bf16(
      __builtin_bit_cast(short8, a), __builtin_bit_cast(short8, b), c, 0, 0, 0);
}

__global__ void __launch_bounds__(512, 2)
uot_kernel(const float* __restrict__ dens, const float* __restrict__ pts,
           float* __restrict__ out, unsigned long long* __restrict__ ws) {
  __shared__ float ymx[256], ymy[256], psi[256], nb[256], tb[256], tps[256];
  __shared__ float tp[2][256];
  __shared__ float red[8];
  __shared__ uint4 Vl4[320];                       // V: 64 rows x 80B (40 u16)
  unsigned short* Vl = (unsigned short*)Vl4;

  const int s = blockIdx.x >> 3, b = blockIdx.x & 7;
  const int ib = b >> 2, jb = b & 3;
  const int i0 = ib * 64, j0 = jb * 32;
  const int t = threadIdx.x, l = t & 63, w = t >> 6;
  const int wi = w >> 1, wj = w & 1;   // f-GEMM frag: rows i0+wi*16, cols j0+wj*16
  const int ii = w >> 2, mi = w & 3;   // g-GEMM tile: rows ii*32 (local), cols mi*64
  const int lr = l & 15, lq = l >> 4;

  unsigned long long* tpair = ws + (size_t)s * 4096;   // [2 par][8 blk][256] u64
  const float* dp = dens + s * 16384;
  const float* pp = pts + s * 512;

  if (t < 256) {
    ymx[t] = pp[2 * t] * (1.f / 256.f);
    ymy[t] = pp[2 * t + 1] * (1.f / 256.f);
    psi[t] = 1.f;
    nb[t]  = 1.f;
  }
  __syncthreads();

  // ---- register tables (iteration-invariant) ----
  uint4 A_f[8], B_f[8], B_g[4];
  uint2 A_t[2][4];
  float a_f[4];
  {
    float gxa = (i0 + wi * 16 + lr + 0.5f) * (1.f / 128.f);
    float gya = (j0 + wj * 16 + lr + 0.5f) * (1.f / 128.f);
    #pragma unroll
    for (int ks = 0; ks < 8; ++ks) {
      unsigned qa[4], qb[4];
      #pragma unroll
      for (int e4 = 0; e4 < 4; ++e4) {
        int m0 = ks * 32 + 8 * lq + 2 * e4;
        float dx0 = gxa - ymx[m0], dx1 = gxa - ymx[m0 + 1];
        float dy0 = gya - ymy[m0], dy1 = gya - ymy[m0 + 1];
        qa[e4] = cvtpk(hexp2(dx0 * dx0 * NEG5L2E), hexp2(dx1 * dx1 * NEG5L2E));
        qb[e4] = cvtpk(hexp2(dy0 * dy0 * NEG5L2E), hexp2(dy1 * dy1 * NEG5L2E));
      }
      A_f[ks] = make_uint4(qa[0], qa[1], qa[2], qa[3]);
      B_f[ks] = make_uint4(qb[0], qb[1], qb[2], qb[3]);
    }
    #pragma unroll
    for (int mt = 0; mt < 4; ++mt) {          // B_g: k = local j, col = m
      float ym = ymy[mi * 64 + mt * 16 + lr];
      unsigned q[4];
      #pragma unroll
      for (int e4 = 0; e4 < 4; ++e4) {
        float g0 = (j0 + 8 * lq + 2 * e4 + 0.5f) * (1.f / 128.f);
        float d0 = g0 - ym, d1 = d0 + (1.f / 128.f);
        q[e4] = cvtpk(hexp2(d0 * d0 * NEG5L2E), hexp2(d1 * d1 * NEG5L2E));
      }
      B_g[mt] = make_uint4(q[0], q[1], q[2], q[3]);
    }
    #pragma unroll
    for (int it = 0; it < 2; ++it)            // A_t: C/D layout of g-GEMM
      #pragma unroll
      for (int mt = 0; mt < 4; ++mt) {
        float ym = ymx[mi * 64 + mt * 16 + lr];
        float g0 = (i0 + ii * 32 + it * 16 + 4 * lq + 0.5f) * (1.f / 128.f);
        float d0 = g0 - ym, d1 = d0 + (1.f / 128.f);
        float d2 = d0 + (2.f / 128.f), d3 = d0 + (3.f / 128.f);
        A_t[it][mt].x = cvtpk(hexp2(d0 * d0 * NEG5L2E), hexp2(d1 * d1 * NEG5L2E));
        A_t[it][mt].y = cvtpk(hexp2(d2 * d2 * NEG5L2E), hexp2(d3 * d3 * NEG5L2E));
      }
    #pragma unroll
    for (int e = 0; e < 4; ++e)               // density frag (C/D layout)
      a_f[e] = fmaxf(dp[(i0 + wi * 16 + 4 * lq + e) * 128 + (j0 + wj * 16 + lr)],
                     1e-8f);
  }

  f32x4 fA;
  unsigned mygen = 0;
  int par = 0;

  // ---- f-update: fully register-fed, zero barriers ----
  auto f_update = [&]() {
    f32x4 acc = {0.f, 0.f, 0.f, 0.f};
    #pragma unroll
    for (int ks = 0; ks < 8; ++ks) {
      int mb = ks * 32 + 8 * lq;
      float4 p0 = *(const float4*)(psi + mb);
      float4 p1 = *(const float4*)(psi + mb + 4);
      const unsigned* ar = (const unsigned*)&A_f[ks];
      uint4 wf;
      wf.x = cvtpk(pklo(ar[0]) * p0.x, pkhi(ar[0]) * p0.y);
      wf.y = cvtpk(pklo(ar[1]) * p0.z, pkhi(ar[1]) * p0.w);
      wf.z = cvtpk(pklo(ar[2]) * p1.x, pkhi(ar[2]) * p1.y);
      wf.w = cvtpk(pklo(ar[3]) * p1.z, pkhi(ar[3]) * p1.w);
      acc = mfma16(wf, B_f[ks], acc);
    }
    fA = acc;
  };

  // ---- g-update. mode 0: phase-A; 1: phase-C; 2: residual ----
  auto g_update = [&](int mode) {
    // V build: V[i][j] = a * s^{-tau}  (block-local, bf16)
    #pragma unroll
    for (int e = 0; e < 4; ++e) {
      float phi = powm(fA[e], -TAU_F);
      int il = wi * 16 + 4 * lq + e;
      int jl = wj * 16 + lr;
      union { float f; unsigned i; } v; v.f = a_f[e] * phi;
      unsigned bi = v.i + 0x7fffu + ((v.i >> 16) & 1u);
      Vl[il * 40 + jl] = (unsigned short)(bi >> 16);
    }
    __syncthreads();
    // g-GEMM: K = 32 local j, single MFMA step per frag
    uint4 vfr[2];
    #pragma unroll
    for (int it = 0; it < 2; ++it)
      vfr[it] = *(const uint4*)(Vl + (ii * 32 + it * 16 + lr) * 40 + 8 * lq);
    f32x4 gA[2][4];
    #pragma unroll
    for (int it = 0; it < 2; ++it)
      #pragma unroll
      for (int mt = 0; mt < 4; ++mt) {
        f32x4 z = {0.f, 0.f, 0.f, 0.f};
        gA[it][mt] = mfma16(vfr[it], B_g[mt], z);
      }
    // t-partial: t^b_m = sum_{i local} A[i][m] * P[i][m]
    #pragma unroll
    for (int mt = 0; mt < 4; ++mt) {
      float acc = 0.f;
      #pragma unroll
      for (int it = 0; it < 2; ++it) {
        uint2 u = A_t[it][mt];
        acc += pklo(u.x) * gA[it][mt][0];
        acc += pkhi(u.x) * gA[it][mt][1];
        acc += pklo(u.y) * gA[it][mt][2];
        acc += pkhi(u.y) * gA[it][mt][3];
      }
      acc += __shfl_xor(acc, 16);
      acc += __shfl_xor(acc, 32);
      if (l < 16) tp[ii][mi * 64 + mt * 16 + lr] = acc;
    }
    __syncthreads();
    const unsigned target = mygen + 1;
    if (t < 256) {
      // publish own (gen|value) word — tag rides with data, no fence needed
      float own = tp[0][t] + tp[1][t];
      union { float f; unsigned i; } ov; ov.f = own;
      unsigned long long pu = ((unsigned long long)target << 32) | ov.i;
      __hip_atomic_store(&tpair[par * 2048 + b * 256 + t], pu,
                         __ATOMIC_RELAXED, __HIP_MEMORY_SCOPE_AGENT);
      // poll all 8 tagged words (incl. own) until generation matches
      float tm;
      bool ok;
      do {
        ok = true; tm = 0.f;
        #pragma unroll
        for (int k = 0; k < 8; ++k) {
          unsigned long long p =
              __hip_atomic_load(&tpair[par * 2048 + k * 256 + t],
                                __ATOMIC_RELAXED, __HIP_MEMORY_SCOPE_AGENT);
          ok &= ((unsigned)(p >> 32) >= target);
          union { unsigned i; float f; } pv; pv.i = (unsigned)p;
          tm += pv.f;
        }
        if (!ok) __builtin_amdgcn_s_sleep(1);
      } while (!ok);
      if (mode == 2) {
        float r   = psi[t] * tm - 1.f;               // residual (b=1 in phase A)
        float nbv = fmaxf(1.f + LAMB_F * r, 1e-8f);  // new_b
        nb[t] = nbv;
        psi[t] = nbv;                                // psi' for phase C start
      } else {
        float ps = powm(tm, -TAU_F);                 // t^{-tau}
        psi[t] = (mode == 1 ? nb[t] : 1.f) * ps;
        tb[t] = tm;
      }
    }
    mygen++;
    par ^= 1;
    __syncthreads();
  };

  // ---- two Sinkhorn runs ----
  #pragma unroll 1
  for (int phase = 0; phase < 2; ++phase) {
    #pragma unroll 1
    for (int iter = 0; iter < 51; ++iter) {
      f_update();
      if (iter < 50) g_update(phase);
    }
    if (phase == 0) g_update(2);
  }

  // ---- loss: 1.05 * ( sum_n a*(1-s^{tau*eps}) + sum_m nb*(1-t^{tau*eps}) ) ----
  float ls = 0.f;
  #pragma unroll
  for (int e = 0; e < 4; ++e)
    ls += a_f[e] * (1.f - powm(fA[e], TEPS_F));
  #pragma unroll
  for (int off = 32; off >= 1; off >>= 1) ls += __shfl_xor(ls, off);
  if (l == 0) red[w] = ls;
  __syncthreads();
  if (t < 256) tps[t] = nb[t] * (1.f - powm(tb[t], TEPS_F));
  __syncthreads();
  if (t < 64) {
    float v = (b == 0) ? (tps[t] + tps[t + 64] + tps[t + 128] + tps[t + 192])
                       : 0.f;
    #pragma unroll
    for (int off = 32; off >= 1; off >>= 1) v += __shfl_xor(v, off);
    if (t == 0) {
      float la = 0.f;
      #pragma unroll
      for (int k = 0; k < 8; ++k) la += red[k];
      atomicAdd(out, 1.05f * (la + v));
    }
  }
}

extern "C" void kernel_launch(void* const* d_in, const int* in_sizes, int n_in,
                              void* d_out, int out_size, void* d_ws, size_t ws_size,
                              hipStream_t stream) {
  const float* dens = (const float*)d_in[0];
  const float* pts  = (const float*)d_in[1];
  float* out = (float*)d_out;
  if (ws_size < 131072) return;   // 4 samples x 32KB (gen|value) pair buffers
  (void)hipMemsetAsync(d_out, 0, (size_t)out_size * sizeof(float), stream);
  (void)hipMemsetAsync(d_ws, 0, 131072, stream);   // gen tags must start at 0
  hipLaunchKernelGGL(uot_kernel, dim3(32), dim3(512), 0, stream,
                     dens, pts, out, (unsigned long long*)d_ws);
}